// Round 2
// baseline (1059155.859 us; speedup 1.0000x reference)
//
#include <hip/hip_runtime.h>
#include <hip/hip_bf16.h>
#include <math.h>

// Problem sizes (fixed)
#define T_STEPS 32768
#define DIM 512
#define HID 1024
#define SD 256            // state dim S
#define G3 (3*HID)        // 3072

// Recurrence partitioning: 256 persistent WGs (= CU count), 256 threads each,
// 1 hidden unit per wave (4 units per WG). Workspace: 8KB h_buf + 32KB flags.
#define NWG 256
#define RBT 256

// ---------------------------------------------------------------------------
// init: h_buf[0] = tanh(h0), zero the progress flags (must happen EVERY call)
// ---------------------------------------------------------------------------
__global__ void init_kernel(const float* __restrict__ h0,
                            float* __restrict__ h_buf,
                            unsigned* __restrict__ flags) {
    int i = threadIdx.x;                  // 1024 threads
    h_buf[i] = tanhf(h0[i]);
    if (i < NWG) flags[i * 32] = 0u;
}

__device__ __forceinline__ float softplus_f(float x) {
    float ax = fabsf(x);
    return fmaxf(x, 0.f) + log1pf(expf(-ax));
}

__device__ __forceinline__ float dot4(float4 a, float4 b) {
    return a.x * b.x + a.y * b.y + a.z * b.z + a.w * b.w;
}

// ---------------------------------------------------------------------------
// persistent fused GRU scan + input GEMM + output GEMM.
// Per step t (t = 0..T inclusive; T+1 iterations):
//   prefetch y_t (regs) -> poll flags >= t -> barrier+fence ->
//   stage h_{t-1} (full 1024) into LDS -> barrier ->
//   [t<T]  per-wave dots (w_hh . h + w_ih . y), 4-value butterfly reduce,
//          gate math, lane0 writes h_t unit -> barrier -> flag release(t+1)
//   [t>0]  out row t-1: 2 cols/WG from staged h, reduce, softplus, store.
// ---------------------------------------------------------------------------
__global__ __launch_bounds__(RBT, 1) void gru_scan(
    const float* __restrict__ y, const float* __restrict__ w_ih,
    const float* __restrict__ w_hh, const float* __restrict__ b,
    const float* __restrict__ bn, const float* __restrict__ w_out,
    const float* __restrict__ b_out, float* __restrict__ out,
    float* __restrict__ h_buf /* [2][HID] */, unsigned* __restrict__ flags) {
    const int tid  = threadIdx.x;
    const int wg   = blockIdx.x;
    const int wv   = tid >> 6;            // wave 0..3
    const int lane = tid & 63;
    const int u    = wg * 4 + wv;         // hidden unit owned by this wave

    const int rowr = u, rowz = HID + u, rown = 2 * HID + u;

    // w_hh rows: 16 elems/lane, k = 4*lane + 256*j
    float4 whr[4], whz[4], whn[4];
    #pragma unroll
    for (int j = 0; j < 4; ++j) {
        int k = 4 * lane + 256 * j;
        whr[j] = *(const float4*)&w_hh[(size_t)rowr * HID + k];
        whz[j] = *(const float4*)&w_hh[(size_t)rowz * HID + k];
        whn[j] = *(const float4*)&w_hh[(size_t)rown * HID + k];
    }
    // w_ih rows: 8 elems/lane, k' = 4*lane + 256*j
    float4 wir[2], wiz[2], win[2];
    #pragma unroll
    for (int j = 0; j < 2; ++j) {
        int k = 4 * lane + 256 * j;
        wir[j] = *(const float4*)&w_ih[(size_t)rowr * DIM + k];
        wiz[j] = *(const float4*)&w_ih[(size_t)rowz * DIM + k];
        win[j] = *(const float4*)&w_ih[(size_t)rown * DIM + k];
    }
    const float br  = b[rowr], bz = b[rowz], bnn = b[rown];
    const float bnu = bn[u];

    // output columns: c = 2*wg + (wv>>1); this wave covers half of k-range
    const int c     = 2 * wg + (wv >> 1);
    const int kbase = (wv & 1) * 512 + 4 * lane;
    const float4 wo0 = *(const float4*)&w_out[(size_t)c * HID + kbase];
    const float4 wo1 = *(const float4*)&w_out[(size_t)c * HID + kbase + 256];
    const float bo  = (tid < 2) ? b_out[2 * wg + tid] : 0.f;

    __shared__ float h_lds[HID];
    __shared__ float ps[4];

    const size_t TS = (size_t)T_STEPS * SD;

    for (int t = 0; t <= T_STEPS; ++t) {
        // prefetch this step's y row (independent of h; hides under the poll)
        float4 yv0, yv1;
        if (t < T_STEPS) {
            yv0 = *(const float4*)&y[(size_t)t * DIM + 4 * lane];
            yv1 = *(const float4*)&y[(size_t)t * DIM + 4 * lane + 256];
        }

        // wait until all WGs have published h_t-1
        if (t > 0) {
            if (tid < NWG) {
                while (__hip_atomic_load(&flags[tid * 32], __ATOMIC_ACQUIRE,
                                         __HIP_MEMORY_SCOPE_AGENT) < (unsigned)t) {
                    __builtin_amdgcn_s_sleep(2);
                }
            }
        }
        __syncthreads();
        __threadfence();   // agent-scope acquire: invalidate stale h lines

        // stage h_{t-1} into LDS (coalesced: 256 threads x float4)
        const float* hb = &h_buf[(t & 1) * HID];
        *(float4*)&h_lds[4 * tid] = *(const float4*)&hb[4 * tid];
        __syncthreads();

        if (t < T_STEPS) {
            float4 hv[4];
            #pragma unroll
            for (int j = 0; j < 4; ++j) hv[j] = *(float4*)&h_lds[4 * lane + 256 * j];

            float sr = 0.f, sz = 0.f, shn = 0.f, sin_ = 0.f;
            #pragma unroll
            for (int j = 0; j < 4; ++j) {
                sr  += dot4(whr[j], hv[j]);
                sz  += dot4(whz[j], hv[j]);
                shn += dot4(whn[j], hv[j]);
            }
            sr   += dot4(wir[0], yv0) + dot4(wir[1], yv1);
            sz   += dot4(wiz[0], yv0) + dot4(wiz[1], yv1);
            sin_ += dot4(win[0], yv0) + dot4(win[1], yv1);

            // butterfly reduce 4 values across the 64-lane wave
            #pragma unroll
            for (int off = 32; off > 0; off >>= 1) {
                sr   += __shfl_xor(sr, off, 64);
                sz   += __shfl_xor(sz, off, 64);
                shn  += __shfl_xor(shn, off, 64);
                sin_ += __shfl_xor(sin_, off, 64);
            }

            float r = 1.f / (1.f + expf(-(sr + br)));
            float z = 1.f / (1.f + expf(-(sz + bz)));
            float n = tanhf(sin_ + bnn + r * (shn + bnu));
            float hp = h_lds[u];
            float hnew = n + z * (hp - n);

            if (lane == 0)
                h_buf[((t + 1) & 1) * HID + u] = hnew;
        }

        __syncthreads();   // drain h_buf stores (vmcnt 0) before release
        if (t < T_STEPS && tid == 0)
            __hip_atomic_store(&flags[wg * 32], (unsigned)(t + 1),
                               __ATOMIC_RELEASE, __HIP_MEMORY_SCOPE_AGENT);

        // output row t-1 from the staged h (overlaps flag propagation)
        if (t > 0) {
            float4 ha  = *(float4*)&h_lds[kbase];
            float4 hb2 = *(float4*)&h_lds[kbase + 256];
            float p = dot4(wo0, ha) + dot4(wo1, hb2);
            #pragma unroll
            for (int off = 32; off > 0; off >>= 1)
                p += __shfl_xor(p, off, 64);
            if (lane == 0) ps[wv] = p;
            __syncthreads();
            if (tid < 2) {
                int cc = 2 * wg + tid;
                float v = ps[2 * tid] + ps[2 * tid + 1] + bo;
                size_t row = (size_t)(t - 1);
                if (cc >= SD) out[TS + row * SD + (cc - SD)] = softplus_f(v);
                else          out[row * SD + cc] = v;
            }
        }
    }
}

// ---------------------------------------------------------------------------
extern "C" void kernel_launch(void* const* d_in, const int* in_sizes, int n_in,
                              void* d_out, int out_size, void* d_ws, size_t ws_size,
                              hipStream_t stream) {
    const float* y     = (const float*)d_in[0];
    const float* h0    = (const float*)d_in[1];
    const float* w_ih  = (const float*)d_in[2];
    const float* w_hh  = (const float*)d_in[3];
    const float* b     = (const float*)d_in[4];
    const float* bn    = (const float*)d_in[5];
    const float* w_out = (const float*)d_in[6];
    const float* b_out = (const float*)d_in[7];
    float* out = (float*)d_out;

    char* ws = (char*)d_ws;
    float* h_buf    = (float*)ws;                         // 2*HID fp32 = 8 KB
    unsigned* flags = (unsigned*)(ws + 2 * HID * 4);      // NWG*32 u32 = 32 KB

    hipLaunchKernelGGL(init_kernel, dim3(1), dim3(1024), 0, stream,
                       h0, h_buf, flags);
    hipLaunchKernelGGL(gru_scan, dim3(NWG), dim3(RBT), 0, stream,
                       y, w_ih, w_hh, b, bn, w_out, b_out, out, h_buf, flags);
}

// Round 3
// 65888.275 us; speedup vs baseline: 16.0750x; 16.0750x over previous
//
#include <hip/hip_runtime.h>
#include <math.h>

// Problem sizes (fixed)
#define T_STEPS 32768
#define DIM 512
#define HID 1024
#define SD 256            // state dim S

// 256 persistent WGs (1 per CU), 256 threads, 1 hidden unit per wave.
#define NWG 256
#define RBT 256

typedef unsigned u32x4 __attribute__((ext_vector_type(4)));
typedef unsigned u32x2 __attribute__((ext_vector_type(2)));

// Pin a loaded float4 into VGPRs: opaque def prevents the compiler from
// sinking/rematerializing the weight loads inside the scan loop
// (round 2: VGPR_Count=68 proved weights were re-fetched every step).
#define PIN4(v) asm volatile("" : "+v"((v).x), "+v"((v).y), "+v"((v).z), "+v"((v).w))

__device__ __forceinline__ float softplus_f(float x) {
    float ax = fabsf(x);
    return fmaxf(x, 0.f) + log1pf(expf(-ax));
}
__device__ __forceinline__ float dot4(float4 a, float4 b) {
    return a.x * b.x + a.y * b.y + a.z * b.z + a.w * b.w;
}

// ---------------------------------------------------------------------------
// init: h_tag[0][i] = {tanh(h0[i]), tag=0}; h_tag[1][i] = {0, 0xFFFFFFFF}.
// Must run every call (tags from the previous timed replay would alias:
// final tags are 32768/32767, which collide with in-call expected tags).
// Plain stores: kernel-end writeback makes them visible to sc1 loads.
// ---------------------------------------------------------------------------
__global__ void init_kernel(const float* __restrict__ h0,
                            u32x2* __restrict__ h_tag) {
    int i = blockIdx.x * 256 + threadIdx.x;    // grid = 8 x 256 = 2048
    u32x2 p;
    if (i < HID) {
        p.x = __float_as_uint(tanhf(h0[i]));
        p.y = 0u;
    } else {
        p.x = 0u;
        p.y = 0xFFFFFFFFu;
    }
    h_tag[i] = p;
}

// ---------------------------------------------------------------------------
// persistent fused scan. Cross-WG h exchange via {val,tag} pairs in LLC:
//   publish: global_store_dwordx2 sc0 sc1 (fire-and-forget, no ack, no flag)
//   consume: spin global_load_dwordx4 sc0 sc1 until all 4 tags == t
// Tag match on ALL 1024 units == full barrier (publishing t implies having
// consumed t-1), so parity double-buffering is WAR-safe.
// ---------------------------------------------------------------------------
__global__ __launch_bounds__(RBT, 1) void gru_scan(
    const float* __restrict__ y, const float* __restrict__ w_ih,
    const float* __restrict__ w_hh, const float* __restrict__ b,
    const float* __restrict__ bn, const float* __restrict__ w_out,
    const float* __restrict__ b_out, float* __restrict__ out,
    u32x2* __restrict__ h_tag /* [2][HID] */) {
    const int tid  = threadIdx.x;
    const int wg   = blockIdx.x;
    const int wv   = tid >> 6;            // wave 0..3
    const int lane = tid & 63;
    const int u    = wg * 4 + wv;         // hidden unit owned by this wave

    const int rowr = u, rowz = HID + u, rown = 2 * HID + u;

    // w_hh rows: 16 elems/lane, k = 4*lane + 256*j
    float4 whr[4], whz[4], whn[4];
    #pragma unroll
    for (int j = 0; j < 4; ++j) {
        int k = 4 * lane + 256 * j;
        whr[j] = *(const float4*)&w_hh[(size_t)rowr * HID + k];
        whz[j] = *(const float4*)&w_hh[(size_t)rowz * HID + k];
        whn[j] = *(const float4*)&w_hh[(size_t)rown * HID + k];
        PIN4(whr[j]); PIN4(whz[j]); PIN4(whn[j]);
    }
    // w_ih rows: 8 elems/lane
    float4 wir[2], wiz[2], win[2];
    #pragma unroll
    for (int j = 0; j < 2; ++j) {
        int k = 4 * lane + 256 * j;
        wir[j] = *(const float4*)&w_ih[(size_t)rowr * DIM + k];
        wiz[j] = *(const float4*)&w_ih[(size_t)rowz * DIM + k];
        win[j] = *(const float4*)&w_ih[(size_t)rown * DIM + k];
        PIN4(wir[j]); PIN4(wiz[j]); PIN4(win[j]);
    }
    const float br  = b[rowr], bz = b[rowz], bnn = b[rown];
    const float bnu = bn[u];

    // output columns: c = 2*wg + (wv>>1), this wave covers half the k-range
    const int c     = 2 * wg + (wv >> 1);
    const int kbase = (wv & 1) * 512 + 4 * lane;
    float4 wo0 = *(const float4*)&w_out[(size_t)c * HID + kbase];
    float4 wo1 = *(const float4*)&w_out[(size_t)c * HID + kbase + 256];
    PIN4(wo0); PIN4(wo1);
    const float bo = (tid < 2) ? b_out[2 * wg + tid] : 0.f;

    __shared__ float h_lds[2][HID];
    __shared__ float ps[2][4];

    const size_t TS = (size_t)T_STEPS * SD;

    for (int t = 0; t <= T_STEPS; ++t) {
        // prefetch this step's y row (plain cached loads, overlap the spin)
        float4 yv0, yv1;
        if (t < T_STEPS) {
            yv0 = *(const float4*)&y[(size_t)t * DIM + 4 * lane];
            yv1 = *(const float4*)&y[(size_t)t * DIM + 4 * lane + 256];
        }

        // spin-consume this thread's 4 {val,tag} pairs of h_t
        u32x4 p0, p1;
        {
            const u32x2* hp = h_tag + (size_t)((t & 1) * HID + 4 * tid);
            const unsigned tg = (unsigned)t;
            while (true) {
                asm volatile(
                    "global_load_dwordx4 %0, %2, off sc0 sc1\n\t"
                    "global_load_dwordx4 %1, %2, off offset:16 sc0 sc1\n\t"
                    "s_waitcnt vmcnt(0)"
                    : "=&v"(p0), "=&v"(p1) : "v"(hp) : "memory");
                if (p0.y == tg && p0.w == tg && p1.y == tg && p1.w == tg) break;
                __builtin_amdgcn_s_sleep(1);
            }
        }
        // stage values into LDS (parity double-buffered; barrier below also
        // guarantees every thread consumed h_t before this WG publishes h_t+1)
        float4 hw;
        hw.x = __uint_as_float(p0.x); hw.y = __uint_as_float(p0.z);
        hw.z = __uint_as_float(p1.x); hw.w = __uint_as_float(p1.z);
        *(float4*)&h_lds[t & 1][4 * tid] = hw;
        __syncthreads();
        const float* hL = h_lds[t & 1];

        if (t < T_STEPS) {
            float4 hv[4];
            #pragma unroll
            for (int j = 0; j < 4; ++j) hv[j] = *(const float4*)&hL[4 * lane + 256 * j];

            float sr = 0.f, sz = 0.f, shn = 0.f, si = 0.f;
            #pragma unroll
            for (int j = 0; j < 4; ++j) {
                sr  += dot4(whr[j], hv[j]);
                sz  += dot4(whz[j], hv[j]);
                shn += dot4(whn[j], hv[j]);
            }
            sr += dot4(wir[0], yv0) + dot4(wir[1], yv1);
            sz += dot4(wiz[0], yv0) + dot4(wiz[1], yv1);
            si += dot4(win[0], yv0) + dot4(win[1], yv1);

            #pragma unroll
            for (int off = 32; off > 0; off >>= 1) {
                sr  += __shfl_xor(sr, off, 64);
                sz  += __shfl_xor(sz, off, 64);
                shn += __shfl_xor(shn, off, 64);
                si  += __shfl_xor(si, off, 64);
            }

            float r = 1.f / (1.f + expf(-(sr + br)));
            float z = 1.f / (1.f + expf(-(sz + bz)));
            float n = tanhf(si + bnn + r * (shn + bnu));
            float hp = hL[u];
            float hnew = n + z * (hp - n);

            if (lane == 0) {
                u32x2 pv; pv.x = __float_as_uint(hnew); pv.y = (unsigned)(t + 1);
                u32x2* pp = h_tag + (size_t)((~t & 1) * HID + u);
                asm volatile("global_store_dwordx2 %0, %1, off sc0 sc1"
                             :: "v"(pp), "v"(pv) : "memory");
            }
        }

        // output row t-1 from staged h_t (off the critical path, after publish)
        if (t > 0) {
            float4 ha  = *(const float4*)&hL[kbase];
            float4 hb2 = *(const float4*)&hL[kbase + 256];
            float p = dot4(wo0, ha) + dot4(wo1, hb2);
            #pragma unroll
            for (int off = 32; off > 0; off >>= 1)
                p += __shfl_xor(p, off, 64);
            if (lane == 0) ps[t & 1][wv] = p;
            __syncthreads();
            if (tid < 2) {
                int cc = 2 * wg + tid;
                float v = ps[t & 1][2 * tid] + ps[t & 1][2 * tid + 1] + bo;
                size_t row = (size_t)(t - 1);
                if (cc >= SD) out[TS + row * SD + (cc - SD)] = softplus_f(v);
                else          out[row * SD + cc] = v;
            }
        }
    }
}

// ---------------------------------------------------------------------------
extern "C" void kernel_launch(void* const* d_in, const int* in_sizes, int n_in,
                              void* d_out, int out_size, void* d_ws, size_t ws_size,
                              hipStream_t stream) {
    const float* y     = (const float*)d_in[0];
    const float* h0    = (const float*)d_in[1];
    const float* w_ih  = (const float*)d_in[2];
    const float* w_hh  = (const float*)d_in[3];
    const float* b     = (const float*)d_in[4];
    const float* bn    = (const float*)d_in[5];
    const float* w_out = (const float*)d_in[6];
    const float* b_out = (const float*)d_in[7];
    float* out = (float*)d_out;

    u32x2* h_tag = (u32x2*)d_ws;   // [2][HID] {val,tag} pairs = 16 KB

    hipLaunchKernelGGL(init_kernel, dim3(8), dim3(256), 0, stream, h0, h_tag);
    hipLaunchKernelGGL(gru_scan, dim3(NWG), dim3(RBT), 0, stream,
                       y, w_ih, w_hh, b, bn, w_out, b_out, out, h_tag);
}

// Round 5
// 65515.533 us; speedup vs baseline: 16.1665x; 1.0057x over previous
//
#include <hip/hip_runtime.h>
#include <math.h>

// Problem sizes (fixed)
#define T_STEPS 32768
#define DIM 512
#define HID 1024
#define SD 256            // state dim S

// 256 persistent WGs (1/CU), 128 threads = 2 independent waves, 2 units/wave.
#define NWG 256
#define RBT 128

typedef unsigned u32x4 __attribute__((ext_vector_type(4)));

// Pin loaded weights into registers: opaque def prevents per-step re-fetch.
#define PIN4(v) asm volatile("" : "+v"((v).x), "+v"((v).y), "+v"((v).z), "+v"((v).w))

__device__ __forceinline__ float dot4(float4 a, float4 b) {
    return a.x * b.x + a.y * b.y + a.z * b.z + a.w * b.w;
}
__device__ __forceinline__ float sigmoid_fast(float x) {
    float e = __builtin_amdgcn_exp2f(-1.4426950408889634f * x);
    return __builtin_amdgcn_rcpf(1.f + e);
}
__device__ __forceinline__ float tanh_fast(float x) {
    float e = __builtin_amdgcn_exp2f(2.8853900817779268f * x);   // exp(2x)
    return 1.f - 2.f * __builtin_amdgcn_rcpf(e + 1.f);
}
__device__ __forceinline__ float softplus_f(float x) {
    float ax = fabsf(x);
    return fmaxf(x, 0.f) + log1pf(expf(-ax));
}

// ---------------------------------------------------------------------------
// h state: u32 word per element, low 2 bits = step tag (t&3), rest = fp32 bits.
// htag[0][i] (even steps), htag[1][i] (odd steps).
// init: buffer0 = tanh(h0) tag 0; buffer1 scrubbed to 0 (even tag — buffer1
// readers only ever expect odd tags, so stale cross-call data can't match).
// Runs every call (replay-safe). Plain stores: kernel-end flush reaches LLC.
// ---------------------------------------------------------------------------
__global__ void init_kernel(const float* __restrict__ h0,
                            unsigned* __restrict__ htag) {
    int i = blockIdx.x * 256 + threadIdx.x;      // grid 4 x 256 = 1024
    unsigned v = __float_as_uint(tanhf(h0[i]));
    htag[i]       = v & ~3u;   // h_0, tag 0
    htag[HID + i] = 0u;        // buffer1 scrub
}

// ---------------------------------------------------------------------------
// persistent fused scan, wave-granular (no LDS, no __syncthreads):
// each wave owns units u0,u0+1; lane l polls h elements 16l..16l+15 (the
// exact elements its dot products consume) via one asm block:
// 4x global_load_dwordx4 sc0 sc1 + s_waitcnt vmcnt(0)  [in-flight regs never
// cross an asm boundary — round-4 lesson]. Publish = single dword store
// sc0 sc1 by lanes 0/32. Poll's vmcnt(0) also orders same-wave publishes,
// which makes the 2-bit tag scheme alias-free (stale is always tag-2 mod 4).
// ---------------------------------------------------------------------------
__global__ __launch_bounds__(RBT, 1) void gru_scan(
    const float* __restrict__ y, const float* __restrict__ h0,
    const float* __restrict__ w_ih, const float* __restrict__ w_hh,
    const float* __restrict__ b, const float* __restrict__ bn,
    const float* __restrict__ w_out, const float* __restrict__ b_out,
    float* __restrict__ out, unsigned* __restrict__ htag /* [2][HID] */) {
    const int tid  = threadIdx.x;
    const int wg   = blockIdx.x;
    const int wv   = tid >> 6;          // wave 0..1
    const int lane = tid & 63;
    const int half = lane >> 5;         // 0: unit u0, 1: unit u0+1
    const int u0   = wg * 4 + wv * 2;
    const int um   = u0 + half;         // unit this half-wave finalizes

    // hidden weights wh[gate][unit][q]: 16 elems/lane at 16*lane (96 VGPRs)
    float4 wh[3][2][4];
    #pragma unroll
    for (int g = 0; g < 3; ++g)
        #pragma unroll
        for (int uu = 0; uu < 2; ++uu) {
            const float* row = &w_hh[(size_t)(g * HID + u0 + uu) * HID + 16 * lane];
            #pragma unroll
            for (int q = 0; q < 4; ++q) {
                wh[g][uu][q] = *(const float4*)&row[4 * q];
                PIN4(wh[g][uu][q]);
            }
        }
    // input weights wi[gate][unit][q]: 8 elems/lane at 8*lane (48 VGPRs)
    float4 wi[3][2][2];
    #pragma unroll
    for (int g = 0; g < 3; ++g)
        #pragma unroll
        for (int uu = 0; uu < 2; ++uu) {
            const float* row = &w_ih[(size_t)(g * HID + u0 + uu) * DIM + 8 * lane];
            #pragma unroll
            for (int q = 0; q < 2; ++q) {
                wi[g][uu][q] = *(const float4*)&row[4 * q];
                PIN4(wi[g][uu][q]);
            }
        }
    // output weights: col c = 2*wg + wv, 16 elems/lane (16 VGPRs)
    const int c = 2 * wg + wv;
    float4 wo[4];
    #pragma unroll
    for (int q = 0; q < 4; ++q) {
        wo[q] = *(const float4*)&w_out[(size_t)c * HID + 16 * lane + 4 * q];
        PIN4(wo[q]);
    }

    const float bi_r = b[um], bi_z = b[HID + um], bi_n = b[2 * HID + um];
    const float bnu  = bn[um];
    const float bo   = b_out[c];

    float hp = tanhf(h0[um]);           // own unit's h, carried in-register

    // y-side pre-reduced gate inputs (+bias) for step t, computed in slack
    float yr, yz, yi;
    {
        float4 ya = *(const float4*)&y[8 * lane];
        float4 yb = *(const float4*)&y[8 * lane + 4];
        float d[6];
        #pragma unroll
        for (int g = 0; g < 3; ++g)
            #pragma unroll
            for (int uu = 0; uu < 2; ++uu)
                d[g * 2 + uu] = dot4(wi[g][uu][0], ya) + dot4(wi[g][uu][1], yb);
        #pragma unroll
        for (int off = 32; off > 0; off >>= 1)
            #pragma unroll
            for (int k = 0; k < 6; ++k)
                d[k] += __shfl_xor(d[k], off, 64);
        yr = (half ? d[1] : d[0]) + bi_r;
        yz = (half ? d[3] : d[2]) + bi_z;
        yi = (half ? d[5] : d[4]) + bi_n;
    }

    const size_t TS = (size_t)T_STEPS * SD;

    for (int t = 0; t <= T_STEPS; ++t) {
        const unsigned tg = (unsigned)t & 3u;
        const unsigned* pa = htag + (size_t)((t & 1) * HID + 16 * lane);

        // ---- spin: 4 loads + vmcnt(0) in ONE asm block (proven pattern) ----
        u32x4 q0, q1, q2, q3;
        for (;;) {
            asm volatile(
                "global_load_dwordx4 %0, %4, off sc0 sc1\n\t"
                "global_load_dwordx4 %1, %4, off offset:16 sc0 sc1\n\t"
                "global_load_dwordx4 %2, %4, off offset:32 sc0 sc1\n\t"
                "global_load_dwordx4 %3, %4, off offset:48 sc0 sc1\n\t"
                "s_waitcnt vmcnt(0)"
                : "=&v"(q0), "=&v"(q1), "=&v"(q2), "=&v"(q3)
                : "v"(pa) : "memory");
            unsigned m = (q0.x ^ tg) | (q0.y ^ tg) | (q0.z ^ tg) | (q0.w ^ tg)
                       | (q1.x ^ tg) | (q1.y ^ tg) | (q1.z ^ tg) | (q1.w ^ tg)
                       | (q2.x ^ tg) | (q2.y ^ tg) | (q2.z ^ tg) | (q2.w ^ tg)
                       | (q3.x ^ tg) | (q3.y ^ tg) | (q3.z ^ tg) | (q3.w ^ tg);
            if ((m & 3u) == 0u) break;
        }
        float4 hv0 = make_float4(__uint_as_float(q0.x), __uint_as_float(q0.y),
                                 __uint_as_float(q0.z), __uint_as_float(q0.w));
        float4 hv1 = make_float4(__uint_as_float(q1.x), __uint_as_float(q1.y),
                                 __uint_as_float(q1.z), __uint_as_float(q1.w));
        float4 hv2 = make_float4(__uint_as_float(q2.x), __uint_as_float(q2.y),
                                 __uint_as_float(q2.z), __uint_as_float(q2.w));
        float4 hv3 = make_float4(__uint_as_float(q3.x), __uint_as_float(q3.y),
                                 __uint_as_float(q3.z), __uint_as_float(q3.w));

        // ---- critical path: 96 FMA -> 6-val butterfly -> gates -> publish ----
        if (t < T_STEPS) {
            float s[6];
            #pragma unroll
            for (int g = 0; g < 3; ++g)
                #pragma unroll
                for (int uu = 0; uu < 2; ++uu)
                    s[g * 2 + uu] = dot4(wh[g][uu][0], hv0) + dot4(wh[g][uu][1], hv1)
                                  + dot4(wh[g][uu][2], hv2) + dot4(wh[g][uu][3], hv3);
            #pragma unroll
            for (int off = 32; off > 0; off >>= 1)
                #pragma unroll
                for (int k = 0; k < 6; ++k)
                    s[k] += __shfl_xor(s[k], off, 64);

            float r = sigmoid_fast((half ? s[1] : s[0]) + yr);
            float z = sigmoid_fast((half ? s[3] : s[2]) + yz);
            float n = tanh_fast(yi + r * ((half ? s[5] : s[4]) + bnu));
            float hnew = n + z * (hp - n);
            hp = hnew;

            if ((lane & 31) == 0) {
                unsigned pv = (__float_as_uint(hnew) & ~3u) | (((unsigned)t + 1u) & 3u);
                unsigned* pp = htag + (size_t)(((t + 1) & 1) * HID + um);
                asm volatile("global_store_dword %0, %1, off sc0 sc1"
                             :: "v"(pp), "v"(pv) : "memory");
            }
        }

        // ---- slack: out row t-1 from h_t (in regs), then y-dots for t+1 ----
        if (t > 0) {
            float p = dot4(wo[0], hv0) + dot4(wo[1], hv1)
                    + dot4(wo[2], hv2) + dot4(wo[3], hv3);
            #pragma unroll
            for (int off = 32; off > 0; off >>= 1)
                p += __shfl_xor(p, off, 64);
            if (lane == 0) {
                float v = p + bo;
                size_t row = (size_t)(t - 1);
                if (c >= SD) out[TS + row * SD + (c - SD)] = softplus_f(v);
                else         out[row * SD + c] = v;
            }
        }

        if (t + 1 < T_STEPS) {
            float4 ya = *(const float4*)&y[(size_t)(t + 1) * DIM + 8 * lane];
            float4 yb = *(const float4*)&y[(size_t)(t + 1) * DIM + 8 * lane + 4];
            float d[6];
            #pragma unroll
            for (int g = 0; g < 3; ++g)
                #pragma unroll
                for (int uu = 0; uu < 2; ++uu)
                    d[g * 2 + uu] = dot4(wi[g][uu][0], ya) + dot4(wi[g][uu][1], yb);
            #pragma unroll
            for (int off = 32; off > 0; off >>= 1)
                #pragma unroll
                for (int k = 0; k < 6; ++k)
                    d[k] += __shfl_xor(d[k], off, 64);
            yr = (half ? d[1] : d[0]) + bi_r;
            yz = (half ? d[3] : d[2]) + bi_z;
            yi = (half ? d[5] : d[4]) + bi_n;
        }
    }
}

// ---------------------------------------------------------------------------
extern "C" void kernel_launch(void* const* d_in, const int* in_sizes, int n_in,
                              void* d_out, int out_size, void* d_ws, size_t ws_size,
                              hipStream_t stream) {
    const float* y     = (const float*)d_in[0];
    const float* h0    = (const float*)d_in[1];
    const float* w_ih  = (const float*)d_in[2];
    const float* w_hh  = (const float*)d_in[3];
    const float* b     = (const float*)d_in[4];
    const float* bn    = (const float*)d_in[5];
    const float* w_out = (const float*)d_in[6];
    const float* b_out = (const float*)d_in[7];
    float* out = (float*)d_out;

    unsigned* htag = (unsigned*)d_ws;   // [2][HID] u32 = 8 KB

    hipLaunchKernelGGL(init_kernel, dim3(4), dim3(256), 0, stream, h0, htag);
    hipLaunchKernelGGL(gru_scan, dim3(NWG), dim3(RBT), 0, stream,
                       y, h0, w_ih, w_hh, b, bn, w_out, b_out, out, htag);
}

// Round 7
// 52106.012 us; speedup vs baseline: 20.3269x; 1.2574x over previous
//
#include <hip/hip_runtime.h>
#include <math.h>

// Problem sizes (fixed)
#define T_STEPS 32768
#define DIM 512
#define HID 1024
#define SD 256            // state dim S

// 256 persistent WGs (1/CU), 128 threads = 2 independent waves, 2 units/wave.
#define NWG 256
#define RBT 128

typedef unsigned u32x4 __attribute__((ext_vector_type(4)));

// Pin loaded weights into registers: opaque def prevents per-step re-fetch.
#define PIN4(v) asm volatile("" : "+v"((v).x), "+v"((v).y), "+v"((v).z), "+v"((v).w))

__device__ __forceinline__ float dot4(float4 a, float4 b) {
    return a.x*b.x + a.y*b.y + a.z*b.z + a.w*b.w;
}
__device__ __forceinline__ float sigmoid_fast(float x) {
    float e = __builtin_amdgcn_exp2f(-1.4426950408889634f * x);
    return __builtin_amdgcn_rcpf(1.f + e);
}
__device__ __forceinline__ float tanh_fast(float x) {
    float e = __builtin_amdgcn_exp2f(2.8853900817779268f * x);   // exp(2x)
    return 1.f - 2.f * __builtin_amdgcn_rcpf(e + 1.f);
}
__device__ __forceinline__ float softplus_f(float x) {
    float ax = fabsf(x);
    return fmaxf(x, 0.f) + log1pf(expf(-ax));
}
__device__ __forceinline__ float4 asf4(u32x4 q) {
    return make_float4(__uint_as_float(q.x), __uint_as_float(q.y),
                       __uint_as_float(q.z), __uint_as_float(q.w));
}

// Exact 64-lane sum: 4 DPP stages (xor1,2,7,8 — full-rank basis within 16)
// + 2 shfl stages (xor16, xor32). DPP = VALU-speed, off the LDS pipe.
__device__ __forceinline__ float wave_sum(float v) {
    int x;
    x = __builtin_amdgcn_mov_dpp(__float_as_int(v), 0xB1,  0xf, 0xf, true); v += __int_as_float(x); // quad_perm 1032 (xor1)
    x = __builtin_amdgcn_mov_dpp(__float_as_int(v), 0x4E,  0xf, 0xf, true); v += __int_as_float(x); // quad_perm 2301 (xor2)
    x = __builtin_amdgcn_mov_dpp(__float_as_int(v), 0x141, 0xf, 0xf, true); v += __int_as_float(x); // row_half_mirror (xor7)
    x = __builtin_amdgcn_mov_dpp(__float_as_int(v), 0x128, 0xf, 0xf, true); v += __int_as_float(x); // row_ror:8 (xor8)
    v += __shfl_xor(v, 16, 64);
    v += __shfl_xor(v, 32, 64);
    return v;
}

// ---------------------------------------------------------------------------
// h state: u32/elem, low 2 bits = step tag (t&3). Buffers by step parity.
// init runs every call (replay-safe; scrubs stale tags).
// ---------------------------------------------------------------------------
__global__ void init_kernel(const float* __restrict__ h0,
                            unsigned* __restrict__ htag) {
    int i = blockIdx.x * 256 + threadIdx.x;      // grid 4 x 256 = 1024
    unsigned v = __float_as_uint(tanhf(h0[i]));
    htag[i]       = v & ~3u;   // h_0, tag 0
    htag[HID + i] = 0u;        // buffer1 scrub (readers expect odd tags)
}

#define TAGCHK(m, tg)                                                          \
    m = ((q0.x ^ tg) | (q0.y ^ tg)) | ((q0.z ^ tg) | (q0.w ^ tg))              \
      | ((q1.x ^ tg) | (q1.y ^ tg)) | ((q1.z ^ tg) | (q1.w ^ tg))              \
      | ((q2.x ^ tg) | (q2.y ^ tg)) | ((q2.z ^ tg) | (q2.w ^ tg))              \
      | ((q3.x ^ tg) | (q3.y ^ tg)) | ((q3.z ^ tg) | (q3.w ^ tg))

// ---------------------------------------------------------------------------
// persistent fused scan, wave-granular (no LDS, no barriers). Identical
// protocol to round 5 (proven). One change: y prefetch for t+1 rides inside
// the FIRST spin sample's asm block (retired by its vmcnt(0)), and is
// consumed from registers in the NEXT iteration's tail -> the loop tail has
// zero vmem-dependent uses, so no compiler vmcnt(0) ever drains the
// just-issued publish store (round-5's hidden serial stall).
// ---------------------------------------------------------------------------
__global__ __launch_bounds__(RBT, 1) void gru_scan(
    const float* __restrict__ y, const float* __restrict__ h0,
    const float* __restrict__ w_ih, const float* __restrict__ w_hh,
    const float* __restrict__ b, const float* __restrict__ bn,
    const float* __restrict__ w_out, const float* __restrict__ b_out,
    float* __restrict__ out, unsigned* __restrict__ htag /* [2][HID] */) {
    const int tid  = threadIdx.x;
    const int wg   = blockIdx.x;
    const int wv   = tid >> 6;          // wave 0..1
    const int lane = tid & 63;
    const int half = lane >> 5;         // 0: unit u0, 1: unit u0+1
    const int u0   = wg * 4 + wv * 2;
    const int um   = u0 + half;         // unit this half-wave finalizes

    // hidden weights wh[gate][unit][q]: 16 elems/lane at 16*lane
    float4 wh[3][2][4];
    #pragma unroll
    for (int g = 0; g < 3; ++g)
        #pragma unroll
        for (int uu = 0; uu < 2; ++uu) {
            const float* row = &w_hh[(size_t)(g * HID + u0 + uu) * HID + 16 * lane];
            #pragma unroll
            for (int q = 0; q < 4; ++q) { wh[g][uu][q] = *(const float4*)&row[4*q]; PIN4(wh[g][uu][q]); }
        }
    // input weights wi[gate][unit][q]: 8 elems/lane at 8*lane
    float4 wi[3][2][2];
    #pragma unroll
    for (int g = 0; g < 3; ++g)
        #pragma unroll
        for (int uu = 0; uu < 2; ++uu) {
            const float* row = &w_ih[(size_t)(g * HID + u0 + uu) * DIM + 8 * lane];
            #pragma unroll
            for (int q = 0; q < 2; ++q) { wi[g][uu][q] = *(const float4*)&row[4*q]; PIN4(wi[g][uu][q]); }
        }
    // output weights: col c = 2*wg + wv, 16 elems/lane
    const int c = 2 * wg + wv;
    float4 wo[4];
    #pragma unroll
    for (int q = 0; q < 4; ++q) {
        wo[q] = *(const float4*)&w_out[(size_t)c * HID + 16 * lane + 4 * q];
        PIN4(wo[q]);
    }

    const float bi_r = b[um], bi_z = b[HID + um], bi_n = b[2 * HID + um];
    const float bnu  = bn[um];
    const float bo   = b_out[c];

    float hp = tanhf(h0[um]);           // own unit's h, carried in-register

    // y-side pre-reduced gate inputs (+bias) for step t (t=0 in prologue)
    float yr, yz, yi;
    {
        float4 ya0 = *(const float4*)&y[8 * lane];
        float4 ya1 = *(const float4*)&y[8 * lane + 4];
        float d[6];
        #pragma unroll
        for (int g = 0; g < 3; ++g)
            #pragma unroll
            for (int uu = 0; uu < 2; ++uu)
                d[g*2+uu] = dot4(wi[g][uu][0], ya0) + dot4(wi[g][uu][1], ya1);
        #pragma unroll
        for (int k = 0; k < 6; ++k) d[k] = wave_sum(d[k]);
        yr = (half ? d[1] : d[0]) + bi_r;
        yz = (half ? d[3] : d[2]) + bi_z;
        yi = (half ? d[5] : d[4]) + bi_n;
    }

    const size_t TS = (size_t)T_STEPS * SD;

    for (int t = 0; t <= T_STEPS; ++t) {
        const unsigned tg = (unsigned)t & 3u;
        const unsigned* pa = htag + (size_t)((t & 1) * HID + 16 * lane);
        const int tn = (t + 1 < T_STEPS) ? (t + 1) : 0;       // OOB clamp
        const float* ya = &y[(size_t)tn * DIM + 8 * lane];

        // ---- first sample fused with y(t+1) prefetch; all retired by the
        // ---- internal vmcnt(0) (nothing in-flight crosses the asm boundary)
        u32x4 q0, q1, q2, q3, yq0, yq1;
        asm volatile(
            "global_load_dwordx4 %[y0], %[ya], off\n\t"
            "global_load_dwordx4 %[y1], %[ya], off offset:16\n\t"
            "global_load_dwordx4 %[q0], %[pa], off sc0 sc1\n\t"
            "global_load_dwordx4 %[q1], %[pa], off offset:16 sc0 sc1\n\t"
            "global_load_dwordx4 %[q2], %[pa], off offset:32 sc0 sc1\n\t"
            "global_load_dwordx4 %[q3], %[pa], off offset:48 sc0 sc1\n\t"
            "s_waitcnt vmcnt(0)"
            : [q0]"=&v"(q0), [q1]"=&v"(q1), [q2]"=&v"(q2), [q3]"=&v"(q3),
              [y0]"=&v"(yq0), [y1]"=&v"(yq1)
            : [pa]"v"(pa), [ya]"v"(ya)
            : "memory");
        unsigned m; TAGCHK(m, tg);
        while ((m & 3u) != 0u) {
            asm volatile(
                "global_load_dwordx4 %[q0], %[pa], off sc0 sc1\n\t"
                "global_load_dwordx4 %[q1], %[pa], off offset:16 sc0 sc1\n\t"
                "global_load_dwordx4 %[q2], %[pa], off offset:32 sc0 sc1\n\t"
                "global_load_dwordx4 %[q3], %[pa], off offset:48 sc0 sc1\n\t"
                "s_waitcnt vmcnt(0)"
                : [q0]"=&v"(q0), [q1]"=&v"(q1), [q2]"=&v"(q2), [q3]"=&v"(q3)
                : [pa]"v"(pa)
                : "memory");
            TAGCHK(m, tg);
        }
        float4 hv0 = asf4(q0), hv1 = asf4(q1), hv2 = asf4(q2), hv3 = asf4(q3);

        // ---- critical path: 96 FMA -> 6-val reduce -> gates -> publish ----
        if (t < T_STEPS) {
            float s[6];
            #pragma unroll
            for (int g = 0; g < 3; ++g)
                #pragma unroll
                for (int uu = 0; uu < 2; ++uu)
                    s[g*2+uu] = dot4(wh[g][uu][0], hv0) + dot4(wh[g][uu][1], hv1)
                              + dot4(wh[g][uu][2], hv2) + dot4(wh[g][uu][3], hv3);
            #pragma unroll
            for (int k = 0; k < 6; ++k) s[k] = wave_sum(s[k]);

            float r = sigmoid_fast((half ? s[1] : s[0]) + yr);
            float z = sigmoid_fast((half ? s[3] : s[2]) + yz);
            float n = tanh_fast(yi + r * ((half ? s[5] : s[4]) + bnu));
            float hnew = n + z * (hp - n);
            hp = hnew;

            if ((lane & 31) == 0) {
                unsigned pv = (__float_as_uint(hnew) & ~3u) | (((unsigned)t + 1u) & 3u);
                unsigned* pp = htag + (size_t)(((t + 1) & 1) * HID + um);
                asm volatile("global_store_dword %0, %1, off sc0 sc1"
                             :: "v"(pp), "v"(pv) : "memory");
            }
            __builtin_amdgcn_sched_barrier(0);   // publish before any tail work
        }

        // ---- tail (registers only; NO vmem-dependent uses -> no waitcnt) ----
        // y-dots for step t+1 from the fused prefetch
        {
            float4 ya0 = asf4(yq0), ya1 = asf4(yq1);
            float d[6];
            #pragma unroll
            for (int g = 0; g < 3; ++g)
                #pragma unroll
                for (int uu = 0; uu < 2; ++uu)
                    d[g*2+uu] = dot4(wi[g][uu][0], ya0) + dot4(wi[g][uu][1], ya1);
            #pragma unroll
            for (int k = 0; k < 6; ++k) d[k] = wave_sum(d[k]);
            yr = (half ? d[1] : d[0]) + bi_r;
            yz = (half ? d[3] : d[2]) + bi_z;
            yi = (half ? d[5] : d[4]) + bi_n;
        }

        // out row t-1 from this iteration's polled h (hs[t-1] = h_t), in regs
        if (t > 0) {
            float p = dot4(wo[0], hv0) + dot4(wo[1], hv1)
                    + dot4(wo[2], hv2) + dot4(wo[3], hv3);
            p = wave_sum(p);
            if (lane == 0) {
                float v = p + bo;
                size_t row = (size_t)(t - 1);
                if (c >= SD) out[TS + row * SD + (c - SD)] = softplus_f(v);
                else         out[row * SD + c] = v;       // fire-and-forget
            }
        }
    }
}

// ---------------------------------------------------------------------------
extern "C" void kernel_launch(void* const* d_in, const int* in_sizes, int n_in,
                              void* d_out, int out_size, void* d_ws, size_t ws_size,
                              hipStream_t stream) {
    const float* y     = (const float*)d_in[0];
    const float* h0    = (const float*)d_in[1];
    const float* w_ih  = (const float*)d_in[2];
    const float* w_hh  = (const float*)d_in[3];
    const float* b     = (const float*)d_in[4];
    const float* bn    = (const float*)d_in[5];
    const float* w_out = (const float*)d_in[6];
    const float* b_out = (const float*)d_in[7];
    float* out = (float*)d_out;

    unsigned* htag = (unsigned*)d_ws;   // [2][HID] u32 = 8 KB

    hipLaunchKernelGGL(init_kernel, dim3(4), dim3(256), 0, stream, h0, htag);
    hipLaunchKernelGGL(gru_scan, dim3(NWG), dim3(RBT), 0, stream,
                       y, h0, w_ih, w_hh, b, bn, w_out, b_out, out, htag);
}